// Round 22
// baseline (2526.641 us; speedup 1.0000x reference)
//
#include <hip/hip_runtime.h>
#include <cstdint>
#include <math.h>

#define NB 16
#define DM 512
#define NH 8
#define DFF_ 2048
#define SMAX 45

typedef unsigned short ushort_t;
typedef __bf16 bf16x8 __attribute__((ext_vector_type(8)));
typedef float f32x4 __attribute__((ext_vector_type(4)));

// ---------------- bf16 helpers ----------------
__device__ __forceinline__ ushort_t f2b(float f) {  // RNE f32 -> bf16 bits
  uint32_t u = __float_as_uint(f);
  uint32_t r = (u + 0x7FFFu + ((u >> 16) & 1u)) >> 16;
  return (ushort_t)r;
}
__device__ __forceinline__ float bu2f(ushort_t x) {
  return __uint_as_float((uint32_t)x << 16);
}
__device__ __forceinline__ float b2f_lo(uint32_t u) { return __uint_as_float(u << 16); }
__device__ __forceinline__ float b2f_hi(uint32_t u) { return __uint_as_float(u & 0xFFFF0000u); }
__device__ __forceinline__ uint32_t pack2(float lo, float hi) {
  return (uint32_t)f2b(lo) | ((uint32_t)f2b(hi) << 16);
}

// ---------------- threefry2x32 (JAX-compatible) ----------------
__host__ __device__ inline void tf2x32(uint32_t k0, uint32_t k1,
                                       uint32_t x0, uint32_t x1,
                                       uint32_t* o0, uint32_t* o1) {
  uint32_t ks0 = k0, ks1 = k1, ks2 = k0 ^ k1 ^ 0x1BD11BDAu;
  x0 += ks0; x1 += ks1;
#define TF_RND(r) { x0 += x1; x1 = (x1 << (r)) | (x1 >> (32 - (r))); x1 ^= x0; }
  TF_RND(13) TF_RND(15) TF_RND(26) TF_RND(6)
  x0 += ks1; x1 += ks2 + 1u;
  TF_RND(17) TF_RND(29) TF_RND(16) TF_RND(24)
  x0 += ks2; x1 += ks0 + 2u;
  TF_RND(13) TF_RND(15) TF_RND(26) TF_RND(6)
  x0 += ks0; x1 += ks1 + 3u;
  TF_RND(17) TF_RND(29) TF_RND(16) TF_RND(24)
  x0 += ks1; x1 += ks2 + 4u;
  TF_RND(13) TF_RND(15) TF_RND(26) TF_RND(6)
  x0 += ks2; x1 += ks0 + 5u;
#undef TF_RND
  *o0 = x0; *o1 = x1;
}

__global__ void gen_idx_kernel(int* __restrict__ idx, uint32_t k0, uint32_t k1,
                               int n, int mask) {
  int j = blockIdx.x * 256 + threadIdx.x;
  if (j >= n) return;
  int half = n >> 1;
  uint32_t o0, o1;
  if (j < half) {
    tf2x32(k0, k1, (uint32_t)j, (uint32_t)(j + half), &o0, &o1);
    idx[j] = (int)(o0 & (uint32_t)mask);
  } else {
    tf2x32(k0, k1, (uint32_t)(j - half), (uint32_t)j, &o0, &o1);
    idx[j] = (int)(o1 & (uint32_t)mask);
  }
}

// ---------------- block reduce helpers (256 threads, wave64) ----------------
__device__ inline float blk_reduce_sum(float v) {
  __shared__ float s[4];
  for (int o = 32; o > 0; o >>= 1) v += __shfl_down(v, o);
  int lane = threadIdx.x & 63, w = threadIdx.x >> 6;
  if (lane == 0) s[w] = v;
  __syncthreads();
  float r = s[0] + s[1] + s[2] + s[3];
  __syncthreads();
  return r;
}

// ---------------- embedding (writes bf16 h, 4 cols/thread) ----------------
__global__ void embed_kernel(const float* __restrict__ x, const float* __restrict__ W,
                             const float* __restrict__ bias, ushort_t* __restrict__ h) {
  size_t gid = (size_t)blockIdx.x * 256 + threadIdx.x;  // over NB*4096*128 quads
  int o4 = (int)(gid & 127) * 4;
  size_t bl = gid >> 7;
  const float* xr = x + bl * 7;
  float xv[7];
#pragma unroll
  for (int i = 0; i < 7; ++i) xv[i] = xr[i];
  float4 acc = *(const float4*)(bias + o4);
#pragma unroll
  for (int i = 0; i < 7; ++i) {
    float4 w4 = *(const float4*)(W + i * 512 + o4);
    acc.x += xv[i] * w4.x;
    acc.y += xv[i] * w4.y;
    acc.z += xv[i] * w4.z;
    acc.w += xv[i] * w4.w;
  }
  ushort4 o;
  o.x = f2b(acc.x); o.y = f2b(acc.y); o.z = f2b(acc.z); o.w = f2b(acc.w);
  *(ushort4*)(h + bl * 512 + o4) = o;
}

// ---------------- weight cast kernels ----------------
__global__ void cast_bf16(const float* __restrict__ src, ushort_t* __restrict__ dst,
                          size_t n) {
  size_t i = ((size_t)blockIdx.x * 256 + threadIdx.x) * 4;
  if (i >= n) return;
  float4 v = *(const float4*)(src + i);
  ushort4 o;
  o.x = f2b(v.x); o.y = f2b(v.y); o.z = f2b(v.z); o.w = f2b(v.w);
  *(ushort4*)(dst + i) = o;
}

// Bt[n*512+k] = bf16(W[k*512+n])   (512x512)
__global__ void castT512(const float* __restrict__ W, ushort_t* __restrict__ Bt) {
  int gid = blockIdx.x * 256 + threadIdx.x;
  int n = gid >> 9, k = gid & 511;
  Bt[gid] = f2b(W[(size_t)k * 512 + n]);
}

// Bt[n*1536 + dt*512 + i] = bf16(convW[n][i][dt])
__global__ void cast_convW(const float* __restrict__ W, ushort_t* __restrict__ Bt) {
  int gid = blockIdx.x * 256 + threadIdx.x;
  int n = gid / 1536, k = gid - n * 1536;
  int dt = k >> 9, ii = k & 511;
  Bt[gid] = f2b(W[((size_t)n * 512 + ii) * 3 + dt]);
}

// concat 3x512 bias -> 1536
__global__ void concat3(const float* __restrict__ a, const float* __restrict__ b,
                        const float* __restrict__ c, float* __restrict__ o) {
  int t = blockIdx.x * 256 + threadIdx.x;
  if (t >= 1536) return;
  o[t] = t < 512 ? a[t] : (t < 1024 ? b[t - 512] : c[t - 1024]);
}

// ---------------- bf16 MFMA GEMM (m97 structure + T2 XOR swizzle + T1 XCD pin) ----
// fast erf: Abramowitz-Stegun 7.1.26, |err| <= 1.5e-7 (<< bf16 rounding)
__device__ __forceinline__ float erf_fast(float x) {
  float ax = fabsf(x);
  float t = 1.0f / fmaf(0.3275911f, ax, 1.0f);
  float p = t * fmaf(t, fmaf(t, fmaf(t, fmaf(t, 1.061405429f, -1.453152027f),
                                     1.421413741f), -0.284496736f), 0.254829592f);
  float r = fmaf(-p, __expf(-ax * ax), 1.0f);
  return copysignf(r, x);
}
__device__ __forceinline__ float gelu_exact(float c) {
  return 0.5f * c * (1.0f + erf_fast(c * 0.70710678118654752f));
}

template <int MODE, int EPI>
__global__ __launch_bounds__(256) void mfma_gemm(
    const ushort_t* __restrict__ A, const ushort_t* __restrict__ Bt,
    const float* __restrict__ bias, float* __restrict__ Cf,
    ushort_t* __restrict__ Cb, const float* __restrict__ bng,
    const float* __restrict__ bnb, int N, int K, int L) {
  __shared__ __align__(16) ushort_t As[128 * 64];
  __shared__ __align__(16) ushort_t Bs[128 * 64];
  const int tid = threadIdx.x;
  const int lane = tid & 63;
  const int wid = tid >> 6;
  const int wr = wid >> 1, wc = wid & 1;
  // T1 XCD bm-pinning: all blocks sharing an A-row-tile (bm) land on one XCD
  int bm, bn;
  {
    int nbn = gridDim.x, nbm = gridDim.y;
    if ((nbm & 7) == 0) {
      int bid = blockIdx.y * nbn + blockIdx.x;
      int xcd = bid & 7;
      int w2 = bid >> 3;
      bm = xcd * (nbm >> 3) + w2 / nbn;
      bn = w2 % nbn;
    } else {
      bm = blockIdx.y;
      bn = blockIdx.x;
    }
  }
  const int ln = lane & 15, lh = lane >> 4;

  f32x4 acc[4][4] = {};

  for (int k0 = 0; k0 < K; k0 += 64) {
    __syncthreads();
#pragma unroll
    for (int it = 0; it < 4; ++it) {
      int c = it * 256 + tid;
      int row = c >> 3;
      int kc = (((c & 7) ^ (row & 7)) << 3);  // swizzled source chunk
      size_t ga;
      if (MODE == 1) {
        int m = bm * 128 + row;
        int b = m / L, tpos = m - b * L;
        int k = k0 + kc;
        int dt = k >> 9, ii = k & 511;
        int tr2 = tpos + dt - 1;
        if (tr2 < 0) tr2 += L;
        if (tr2 >= L) tr2 -= L;
        ga = ((size_t)(b * L + tr2)) * 512 + ii;
      } else {
        ga = (size_t)(bm * 128 + row) * K + k0 + kc;
      }
      __builtin_amdgcn_global_load_lds(
          (const __attribute__((address_space(1))) void*)(A + ga),
          (__attribute__((address_space(3))) void*)(As + c * 8), 16, 0, 0);
      size_t gb = (size_t)(bn * 128 + row) * K + k0 + kc;
      __builtin_amdgcn_global_load_lds(
          (const __attribute__((address_space(1))) void*)(Bt + gb),
          (__attribute__((address_space(3))) void*)(Bs + c * 8), 16, 0, 0);
    }
    __syncthreads();
#pragma unroll
    for (int kk = 0; kk < 2; ++kk) {
      bf16x8 af[4], bf_[4];
#pragma unroll
      for (int m = 0; m < 4; ++m) {
        int ar = wr * 64 + m * 16 + ln;
        int aoff = (kk * 32 + lh * 8) ^ ((ar & 7) << 3);
        af[m] = *(const bf16x8*)&As[ar * 64 + aoff];
      }
#pragma unroll
      for (int n = 0; n < 4; ++n) {
        int br = wc * 64 + n * 16 + ln;
        int boff = (kk * 32 + lh * 8) ^ ((br & 7) << 3);
        bf_[n] = *(const bf16x8*)&Bs[br * 64 + boff];
      }
#pragma unroll
      for (int m = 0; m < 4; ++m)
#pragma unroll
        for (int n = 0; n < 4; ++n)
          acc[m][n] =
              __builtin_amdgcn_mfma_f32_16x16x32_bf16(af[m], bf_[n], acc[m][n], 0, 0, 0);
    }
  }

  const float bnscale = 0.9999950000374996f;  // 1/sqrt(1+1e-5)
#pragma unroll
  for (int m = 0; m < 4; ++m) {
    int row = bm * 128 + wr * 64 + m * 16 + lh * 4;
#pragma unroll
    for (int n = 0; n < 4; ++n) {
      int col = bn * 128 + wc * 64 + n * 16 + ln;
      float bsv = bias[col];
#pragma unroll
      for (int r = 0; r < 4; ++r) {
        float cval = acc[m][n][r] + bsv;
        if (MODE == 2) {
          ushort_t* dst = Cb + (size_t)(bn >> 2) * (size_t)L;  // L = CBseg
          dst[(size_t)(row + r) * 512 + (col & 511)] = f2b(cval);
        } else {
          size_t oi = (size_t)(row + r) * N + col;
          if (EPI == 0) {
            Cb[oi] = f2b(cval);
          } else if (EPI == 1) {
            Cb[oi] = f2b(cval + bu2f(Cb[oi]));
          } else if (EPI == 2) {
            Cb[oi] = f2b(gelu_exact(cval));
          } else {
            float c2 = cval * bnscale * bng[col] + bnb[col];
            Cf[oi] = c2 > 0.0f ? c2 : __expf(c2) - 1.0f;
          }
        }
      }
    }
  }
}

// ---------------- LN (in-place on bf16 h, packed uint per thread) ----------------
__global__ __launch_bounds__(256) void ln_inplace(ushort_t* __restrict__ h,
                                                  const float* __restrict__ g,
                                                  const float* __restrict__ b) {
  size_t row = blockIdx.x;
  uint32_t* hr = (uint32_t*)(h + row * 512);
  int t = threadIdx.x;
  uint32_t u = hr[t];
  float x0 = b2f_lo(u), x1 = b2f_hi(u);
  float mean = blk_reduce_sum(x0 + x1) * (1.0f / 512.0f);
  float d0 = x0 - mean, d1 = x1 - mean;
  float var = blk_reduce_sum(d0 * d0 + d1 * d1) * (1.0f / 512.0f);
  float rstd = rsqrtf(var + 1e-5f);
  float y0 = d0 * rstd * g[2 * t] + b[2 * t];
  float y1 = d1 * rstd * g[2 * t + 1] + b[2 * t + 1];
  hr[t] = pack2(y0, y1);
}

// ---------------- prob-sparse M scores: one wave per (b,l), 5-way unrolled -------
__device__ __forceinline__ float dot8q(const float* __restrict__ qf, uint4 ku) {
  return qf[0] * b2f_lo(ku.x) + qf[1] * b2f_hi(ku.x) +
         qf[2] * b2f_lo(ku.y) + qf[3] * b2f_hi(ku.y) +
         qf[4] * b2f_lo(ku.z) + qf[5] * b2f_hi(ku.z) +
         qf[6] * b2f_lo(ku.w) + qf[7] * b2f_hi(ku.w);
}

__global__ __launch_bounds__(256) void prob_scores_wave(const ushort_t* __restrict__ q,
                                                        const ushort_t* __restrict__ k,
                                                        const int* __restrict__ idx,
                                                        float* __restrict__ Mout,
                                                        int L, int S, int CBl) {
  int bid = blockIdx.x;
  int w = threadIdx.x >> 6;
  int lane = threadIdx.x & 63;
  int nxb = CBl < 8 ? CBl : 8;
  int gpb = 8 / nxb;
  int bmul = CBl / nxb;
  int xcd = bid & 7;
  int rest = bid >> 3;
  int b = (xcd / gpb) * bmul + (rest % bmul);
  int li = (rest / bmul) * gpb + (xcd % gpb);
  int l = li * 4 + w;

  const ushort_t* qr = q + ((size_t)(b * L + l)) * 512 + lane * 8;
  uint4 qu = *(const uint4*)qr;
  float qf[8];
  qf[0] = b2f_lo(qu.x); qf[1] = b2f_hi(qu.x);
  qf[2] = b2f_lo(qu.y); qf[3] = b2f_hi(qu.y);
  qf[4] = b2f_lo(qu.z); qf[5] = b2f_hi(qu.z);
  qf[6] = b2f_lo(qu.w); qf[7] = b2f_hi(qu.w);
  const int* il = idx + l * S;
  const ushort_t* kb = k + (size_t)b * L * 512 + lane * 8;
  float m = -INFINITY, ssum = 0.0f;
  for (int s = 0; s < S; s += 5) {
    uint4 k0v = *(const uint4*)(kb + (size_t)il[s + 0] * 512);
    uint4 k1v = *(const uint4*)(kb + (size_t)il[s + 1] * 512);
    uint4 k2v = *(const uint4*)(kb + (size_t)il[s + 2] * 512);
    uint4 k3v = *(const uint4*)(kb + (size_t)il[s + 3] * 512);
    uint4 k4v = *(const uint4*)(kb + (size_t)il[s + 4] * 512);
    float d0 = dot8q(qf, k0v);
    float d1 = dot8q(qf, k1v);
    float d2 = dot8q(qf, k2v);
    float d3 = dot8q(qf, k3v);
    float d4 = dot8q(qf, k4v);
    d0 += __shfl_xor(d0, 1); d1 += __shfl_xor(d1, 1); d2 += __shfl_xor(d2, 1);
    d3 += __shfl_xor(d3, 1); d4 += __shfl_xor(d4, 1);
    d0 += __shfl_xor(d0, 2); d1 += __shfl_xor(d1, 2); d2 += __shfl_xor(d2, 2);
    d3 += __shfl_xor(d3, 2); d4 += __shfl_xor(d4, 2);
    d0 += __shfl_xor(d0, 4); d1 += __shfl_xor(d1, 4); d2 += __shfl_xor(d2, 4);
    d3 += __shfl_xor(d3, 4); d4 += __shfl_xor(d4, 4);
    m = fmaxf(m, fmaxf(fmaxf(d0, d1), fmaxf(d2, fmaxf(d3, d4))));
    ssum += (d0 + d1) + (d2 + (d3 + d4));
  }
  if ((lane & 7) == 0) {
    int hh = lane >> 3;
    Mout[((size_t)(b * 8 + hh)) * L + l] = m - ssum / (float)L;
  }
}

// ---------------- top-k via 4-pass radix select ----------------
__global__ __launch_bounds__(256) void topk_kernel(const float* __restrict__ Mbuf,
                                                   int* __restrict__ top_idx,
                                                   int L, int S) {
  int bh = blockIdx.x;
  __shared__ uint32_t keys[4096];
  __shared__ int hist[256];
  __shared__ int sh_bin, sh_found, sh_cnt;
  const float* Mr = Mbuf + (size_t)bh * L;
  int t = threadIdx.x;

  for (int j = t; j < L; j += 256) {
    uint32_t u = __float_as_uint(Mr[j]);
    keys[j] = (u & 0x80000000u) ? ~u : (u | 0x80000000u);
  }
  if (t == 0) sh_cnt = 0;
  __syncthreads();

  uint32_t prefix = 0;
  int found = 0;
  for (int p = 24; p >= 0; p -= 8) {
    hist[t] = 0;
    __syncthreads();
    for (int j = t; j < L; j += 256) {
      uint32_t key = keys[j];
      bool match = (p == 24) || ((key >> (p + 8)) == (prefix >> (p + 8)));
      if (match) atomicAdd(&hist[(key >> p) & 255], 1);
    }
    __syncthreads();
    for (int o = 1; o < 256; o <<= 1) {
      int add = (t + o < 256) ? hist[t + o] : 0;
      __syncthreads();
      hist[t] += add;
      __syncthreads();
    }
    int sufIncl = hist[t];
    int sufExcl = (t < 255) ? hist[t + 1] : 0;
    int needv = S - found;
    if (sufExcl < needv && needv <= sufIncl) { sh_bin = t; sh_found = found + sufExcl; }
    __syncthreads();
    prefix |= (uint32_t)sh_bin << p;
    found = sh_found;
    __syncthreads();
  }

  uint32_t tau = prefix;
  int r = S - found;
  int chunk = L >> 8;
  int base = t * chunk;
  int localEq = 0;
  for (int i = 0; i < chunk; ++i) localEq += (keys[base + i] == tau) ? 1 : 0;
  hist[t] = localEq;
  __syncthreads();
  for (int o = 1; o < 256; o <<= 1) {
    int add = (t >= o) ? hist[t - o] : 0;
    __syncthreads();
    hist[t] += add;
    __syncthreads();
  }
  int myRank = hist[t] - localEq;
  for (int i = 0; i < chunk; ++i) {
    uint32_t key = keys[base + i];
    bool isEq = (key == tau);
    bool sel = (key > tau) || (isEq && myRank < r);
    if (isEq) myRank++;
    if (sel) {
      int slot = atomicAdd(&sh_cnt, 1);
      top_idx[bh * S + slot] = base + i;
    }
  }
}

// ---------------- mean of V: stage 1 (coalesced column partial sums) ----------------
__global__ __launch_bounds__(256) void mean_v_partial(const ushort_t* __restrict__ v,
                                                      float* __restrict__ part, int L) {
  int b = blockIdx.x;
  int chunk = blockIdx.y;
  int t = threadIdx.x;
  int c = t * 2;
  const ushort_t* base = v + ((size_t)b * L + (size_t)chunk * 256) * 512 + c;
  float a0 = 0.0f, a1 = 0.0f;
#pragma unroll 8
  for (int r = 0; r < 256; ++r) {
    uint32_t u = *(const uint32_t*)(base + (size_t)r * 512);
    a0 += b2f_lo(u);
    a1 += b2f_hi(u);
  }
  float* p = part + ((size_t)b * 16 + chunk) * 512 + c;
  p[0] = a0;
  p[1] = a1;
}

// ---------------- mean of V: stage 2 ----------------
__global__ void mean_v_finish(const float* __restrict__ part, float* __restrict__ mv,
                              int L, int nchunks) {
  int b = blockIdx.x;
  int c = threadIdx.x;  // 512 threads
  float s = 0.0f;
  for (int k = 0; k < nchunks; ++k) s += part[((size_t)b * 16 + k) * 512 + c];
  mv[b * 512 + c] = s / (float)L;
}

// ---------------- fill ctx (bf16) with broadcast mean ----------------
__global__ void fill_ctx(ushort_t* __restrict__ ctx, const float* __restrict__ mv,
                         int L) {
  size_t gid = (size_t)blockIdx.x * 256 + threadIdx.x;  // CB*L*512
  int c = (int)(gid & 511);
  size_t bl = gid >> 9;
  int b = (int)(bl / (size_t)L);
  ctx[gid] = f2b(mv[b * 512 + c]);
}

// ---------------- fused flash attention (MFMA QK^T + PV; no-max softmax) ----------
__global__ __launch_bounds__(256) void flash_attn(const ushort_t* __restrict__ q,
                                                  const ushort_t* __restrict__ k,
                                                  const ushort_t* __restrict__ v,
                                                  const int* __restrict__ top_idx,
                                                  float* __restrict__ pz,
                                                  float* __restrict__ po,
                                                  int L, int S, int CBNH) {
  __shared__ __align__(16) ushort_t qs[48 * 64];   // [query][d]
  __shared__ __align__(16) ushort_t Kt[64 * 64];   // [key][d]
  __shared__ __align__(16) ushort_t Vt[64 * 64];   // [d][key] (transposed)
  __shared__ __align__(16) ushort_t Ps[48 * 64];   // [query][key] bf16
  __shared__ float zpart[4][48];
  int bh = blockIdx.y, js = blockIdx.x;
  int hh = bh & 7, b = bh >> 3;
  int t = threadIdx.x;
  int lane = t & 63, w = t >> 6;
  int ln = lane & 15, lh = lane >> 4;
  int j0 = js * 64;

  // stage qs: 48 rows x 8 chunks, zero-pad rows >= S
  for (int e = t; e < 48 * 8; e += 256) {
    int u = e >> 3, c = e & 7;
    uint4 val = make_uint4(0u, 0u, 0u, 0u);
    if (u < S) {
      int l = top_idx[bh * S + u];
      val = *(const uint4*)(q + ((size_t)(b * L + l)) * 512 + hh * 64 + c * 8);
    }
    *(uint4*)(qs + u * 64 + ((c ^ (u & 7)) << 3)) = val;
  }
  // stage Kt [key][d] and Vt [d][key]
  for (int e = t; e < 64 * 8; e += 256) {
    int j = e >> 3, c = e & 7;
    uint4 kv = *(const uint4*)(k + ((size_t)(b * L + j0 + j)) * 512 + hh * 64 + c * 8);
    *(uint4*)(Kt + j * 64 + ((c ^ (j & 7)) << 3)) = kv;
    uint4 vv = *(const uint4*)(v + ((size_t)(b * L + j0 + j)) * 512 + hh * 64 + c * 8);
    const ushort_t* pv8 = (const ushort_t*)&vv;
#pragma unroll
    for (int ee = 0; ee < 8; ++ee) {
      int d = c * 8 + ee;
      Vt[d * 64 + (((j >> 3) ^ (d & 7)) << 3) + (j & 7)] = pv8[ee];
    }
  }
  __syncthreads();

  // ---- QK^T: wave w owns key tile [w*16, w*16+16) ----
  f32x4 sacc[3] = {};
#pragma unroll
  for (int kk = 0; kk < 2; ++kk) {
    int j = w * 16 + ln;
    bf16x8 bfr = *(const bf16x8*)&Kt[j * 64 + (((kk * 4 + lh) ^ (j & 7)) << 3)];
#pragma unroll
    for (int qm = 0; qm < 3; ++qm) {
      int u = qm * 16 + ln;
      bf16x8 af = *(const bf16x8*)&qs[u * 64 + (((kk * 4 + lh) ^ (u & 7)) << 3)];
      sacc[qm] = __builtin_amdgcn_mfma_f32_16x16x32_bf16(af, bfr, sacc[qm], 0, 0, 0);
    }
  }
  // P = exp(S/8) -> bf16 Ps; z partials per 16-lane group
#pragma unroll
  for (int qm = 0; qm < 3; ++qm) {
#pragma unroll
    for (int r = 0; r < 4; ++r) {
      int u = qm * 16 + lh * 4 + r;
      float P = __expf(sacc[qm][r] * 0.125f);
      ushort_t Pb = f2b(P);
      int key = w * 16 + ln;
      Ps[u * 64 + (((key >> 3) ^ (u & 7)) << 3) + (key & 7)] = Pb;
      float ps = bu2f(Pb);
      ps += __shfl_xor(ps, 1);
      ps += __shfl_xor(ps, 2);
      ps += __shfl_xor(ps, 4);
      ps += __shfl_xor(ps, 8);
      if (ln == 0) zpart[w][u] = ps;
    }
  }
  __syncthreads();

  // ---- PV: wave w owns d tile [w*16, w*16+16) ----
  f32x4 oacc[3] = {};
#pragma unroll
  for (int kk = 0; kk < 2; ++kk) {
    int d = w * 16 + ln;
    bf16x8 bfr = *(const bf16x8*)&Vt[d * 64 + (((kk * 4 + lh) ^ (d & 7)) << 3)];
#pragma unroll
    for (int qm = 0; qm < 3; ++qm) {
      int u = qm * 16 + ln;
      bf16x8 af = *(const bf16x8*)&Ps[u * 64 + (((kk * 4 + lh) ^ (u & 7)) << 3)];
      oacc[qm] = __builtin_amdgcn_mfma_f32_16x16x32_bf16(af, bfr, oacc[qm], 0, 0, 0);
    }
  }
  size_t base = (size_t)js * CBNH + bh;
#pragma unroll
  for (int qm = 0; qm < 3; ++qm) {
#pragma unroll
    for (int r = 0; r < 4; ++r) {
      int u = qm * 16 + lh * 4 + r;
      if (u < S) po[(base * SMAX + u) * 64 + w * 16 + ln] = oacc[qm][r];
    }
  }
  if (t < S) pz[base * SMAX + t] =
      zpart[0][t] + zpart[1][t] + zpart[2][t] + zpart[3][t];
}

// ---------------- combine flash partials, /Z, scatter into ctx ----------------
__global__ void flash_finish(const float* __restrict__ pz, const float* __restrict__ po,
                             const int* __restrict__ top_idx, ushort_t* __restrict__ ctx,
                             int L, int S, int CBNH, int fj) {
  int gid = blockIdx.x * 256 + threadIdx.x;  // over CBNH*S*64
  if (gid >= CBNH * S * 64) return;
  int d = gid & 63;
  int r = gid >> 6;  // bh*S + u
  int u = r % S, bh = r / S;
  int hh = bh & 7, b = bh >> 3;
  float Z = 0.0f, O = 0.0f;
  for (int js = 0; js < fj; ++js) {
    size_t pi = ((size_t)js * CBNH + bh) * SMAX + u;
    Z += pz[pi];
    O += po[pi * 64 + d];
  }
  int l = top_idx[bh * S + u];
  ctx[((size_t)(b * L + l)) * 512 + hh * 64 + d] = f2b(O / Z);
}

// ---------------- maxpool window 3 stride 2 (f32 in, bf16 out) ----------------
__global__ void maxpool_kernel(const float* __restrict__ y, ushort_t* __restrict__ hout,
                               int L) {
  size_t gid = (size_t)blockIdx.x * 256 + threadIdx.x;  // CB*(L/2)*512
  int Lh = L >> 1;
  int o = (int)(gid & 511);
  size_t bj = gid >> 9;
  int j = (int)(bj % (size_t)Lh);
  int b = (int)(bj / (size_t)Lh);
  const float* base = y + ((size_t)(b * L + 2 * j)) * 512 + o;
  float mx = base[0];
  if (j > 0) mx = fmaxf(mx, base[-512]);
  mx = fmaxf(mx, base[512]);
  hout[gid] = f2b(mx);
}

// ---------------- final LN + projection (bf16 h) ----------------
__global__ __launch_bounds__(256) void final_ln_proj(const ushort_t* __restrict__ h,
                                                     const float* __restrict__ g,
                                                     const float* __restrict__ bb,
                                                     const float* __restrict__ pw,
                                                     const float* __restrict__ pb,
                                                     float* __restrict__ out, int L) {
  int b = blockIdx.x / 47, l = blockIdx.x % 47;
  const uint32_t* hr = (const uint32_t*)(h + ((size_t)(b * L + l)) * 512);
  int t = threadIdx.x;
  uint32_t u = hr[t];
  float x0 = b2f_lo(u), x1 = b2f_hi(u);
  float mean = blk_reduce_sum(x0 + x1) * (1.0f / 512.0f);
  float d0 = x0 - mean, d1 = x1 - mean;
  float var = blk_reduce_sum(d0 * d0 + d1 * d1) * (1.0f / 512.0f);
  float rstd = rsqrtf(var + 1e-5f);
  float y0 = d0 * rstd * g[2 * t] + bb[2 * t];
  float y1 = d1 * rstd * g[2 * t + 1] + bb[2 * t + 1];
  float dot = blk_reduce_sum(y0 * pw[2 * t] + y1 * pw[2 * t + 1]);
  if (t == 0) out[b * 47 + l] = dot + pb[0];
}

// ---------------- launcher ----------------
extern "C" void kernel_launch(void* const* d_in, const int* in_sizes, int n_in,
                              void* d_out, int out_size, void* d_ws, size_t ws_size,
                              hipStream_t stream) {
  const float* x = (const float*)d_in[0];
  const float* emb_W = (const float*)d_in[1];
  const float* emb_b = (const float*)d_in[2];
  const float* Wq = (const float*)d_in[3];
  const float* bq = (const float*)d_in[4];
  const float* Wk = (const float*)d_in[5];
  const float* bk = (const float*)d_in[6];
  const float* Wv = (const float*)d_in[7];
  const float* bv = (const float*)d_in[8];
  const float* Wo = (const float*)d_in[9];
  const float* bo = (const float*)d_in[10];
  const float* fW1 = (const float*)d_in[11];
  const float* fb1 = (const float*)d_in[12];
  const float* fW2 = (const float*)d_in[13];
  const float* fb2 = (const float*)d_in[14];
  const float* ln1g = (const float*)d_in[15];
  const float* ln1b = (const float*)d_in[16];
  const float* ln2g = (const float*)d_in[17];
  const float* ln2b = (const float*)d_in[18];
  const float* cW = (const float*)d_in[19];
  const float* cb = (const float*)d_in[20];
  const float* bng = (const float*)d_in[21];
  const float* bnb = (const float*)d_in[22];
  const float* flng = (const float*)d_in[23];
  const float* flnb = (const float*)d_in[24];
  const float* pW = (const float*)d_in[25];
  const float* pb = (const float*)d_in[26];
  float* out = (float*)d_out;

  // base batch-group size from ws_size (try 16, 8, 4, 2, 1)
  // need(CB0) = 19,086,848 + CB0 * 5,724,672 floats
  int CB0 = 16;
  while (CB0 > 1) {
    size_t need = 19086848ull + (size_t)CB0 * 5724672ull;
    if (need * 4 <= ws_size) break;
    CB0 >>= 1;
  }
  const size_t CBseg = (size_t)CB0 * 2097152ull;  // CB0*4096*512 (bf16 elems)

  float* ws = (float*)d_ws;
  size_t off = 0;
  ushort_t* h = (ushort_t*)ws;             off += 16777216ull;  // NB*4096*512 bf16
  ushort_t* wbase = (ushort_t*)(ws + off); off += 1966080ull;
  ushort_t* WqkvT = wbase;                 // 1536 x 512 (q rows, k rows, v rows)
  ushort_t* WoT = wbase + 786432;
  ushort_t* W1b = wbase + 1048576;
  ushort_t* W2b = wbase + 2097152;
  ushort_t* Wcb = wbase + 3145728;
  float* bqkv = ws + off;                  off += 1536ull;
  ushort_t* gArea = (ushort_t*)(ws + off); off += 2ull * CBseg;  // 4 segs bf16
  ushort_t* qb = gArea;
  ushort_t* kbuf = gArea + CBseg;
  ushort_t* vb = gArea + 2 * CBseg;
  ushort_t* ctxb = gArea + 3 * CBseg;
  ushort_t* ybuf = gArea;        // spans all 4 segs during FF (R x 2048 bf16)
  float* convY = (float*)gArea;  // spans first 2 segs during conv (CBseg f32)
  float* Mbuf = ws + off;                  off += (size_t)CB0 * 32768;
  float* mv = ws + off;                    off += 8192ull;
  int* topidx = (int*)(ws + off);          off += 6144ull;
  int* idxbuf = (int*)(ws + off);          off += 196608ull;
  float* pzb = ws + off;                   off += (size_t)CB0 * 23040;
  float* pob = ws + off;                   off += (size_t)CB0 * 1474560;
  float* mvpart = ws + off;                off += 131072ull;

  // embedding (bf16 h)
  {
    size_t total = (size_t)NB * 4096 * 128;
    embed_kernel<<<(int)(total / 256), 256, 0, stream>>>(x, emb_W, emb_b, h);
  }

  int L = 4096;
  for (int i = 0; i < 3; ++i) {
    int S = (i == 0) ? 45 : (i == 1) ? 40 : 35;
    int CBl = CB0 * (4096 / L);
    if (CBl > NB) CBl = NB;
    int ngroups = NB / CBl;
    int CBNHl = CBl * NH;
    int Mg = CBl * L;
    size_t segL = (size_t)Mg * 512;
    int fj = L / 64;

    // per-layer weight casts
    castT512<<<1024, 256, 0, stream>>>(Wq + (size_t)i * 262144, WqkvT);
    castT512<<<1024, 256, 0, stream>>>(Wk + (size_t)i * 262144, WqkvT + 262144);
    castT512<<<1024, 256, 0, stream>>>(Wv + (size_t)i * 262144, WqkvT + 524288);
    castT512<<<1024, 256, 0, stream>>>(Wo + (size_t)i * 262144, WoT);
    cast_bf16<<<1024, 256, 0, stream>>>(fW1 + (size_t)i * 1048576, W1b, 1048576);
    cast_bf16<<<1024, 256, 0, stream>>>(fW2 + (size_t)i * 1048576, W2b, 1048576);
    if (i < 2) cast_convW<<<3072, 256, 0, stream>>>(cW + (size_t)i * 786432, Wcb);
    concat3<<<6, 256, 0, stream>>>(bq + i * DM, bk + i * DM, bv + i * DM, bqkv);

    // JAX randint key
    uint32_t fa, fbk;
    tf2x32(0u, 42u, 0u, (uint32_t)i, &fa, &fbk);
    uint32_t a0, b0, a1, b1;
    tf2x32(fa, fbk, 0u, 2u, &a0, &b0);
    tf2x32(fa, fbk, 1u, 3u, &a1, &b1);
    int n = L * S;
    gen_idx_kernel<<<(n + 255) / 256, 256, 0, stream>>>(idxbuf, b0, b1, n, L - 1);

    // ---- attention per batch group ----
    for (int g = 0; g < ngroups; ++g) {
      ushort_t* hg = h + (size_t)g * segL;
      dim3 gqkv(12, Mg / 128);
      mfma_gemm<2, 0><<<gqkv, 256, 0, stream>>>(hg, WqkvT, bqkv, nullptr, qb,
                                                nullptr, nullptr, 1536, 512,
                                                (int)CBseg);

      prob_scores_wave<<<(CBl * L) / 4, 256, 0, stream>>>(qb, kbuf, idxbuf, Mbuf,
                                                          L, S, CBl);
      topk_kernel<<<CBNHl, 256, 0, stream>>>(Mbuf, topidx, L, S);

      mean_v_partial<<<dim3(CBl, L / 256), 256, 0, stream>>>(vb, mvpart, L);
      mean_v_finish<<<CBl, 512, 0, stream>>>(mvpart, mv, L, L / 256);
      fill_ctx<<<(int)(segL / 256), 256, 0, stream>>>(ctxb, mv, L);
      flash_attn<<<dim3(fj, CBNHl), 256, 0, stream>>>(qb, kbuf, vb, topidx,
                                                      pzb, pob, L, S, CBNHl);
      flash_finish<<<(CBNHl * S * 64 + 255) / 256, 256, 0, stream>>>(
          pzb, pob, topidx, ctxb, L, S, CBNHl, fj);

      dim3 gq(4, Mg / 128);
      mfma_gemm<0, 1><<<gq, 256, 0, stream>>>(ctxb, WoT, bo + i * DM, nullptr, hg,
                                              nullptr, nullptr, 512, 512, 0);
    }
    ln_inplace<<<NB * L, 256, 0, stream>>>(h, ln1g + i * DM, ln1b + i * DM);

    // ---- FF row-chunked ----
    int rows = NB * L;
    int R = CB0 * 4096;
    if (R > rows) R = rows;
    for (int r0 = 0; r0 < rows; r0 += R) {
      ushort_t* hr = h + (size_t)r0 * 512;
      dim3 g1(16, R / 128);
      mfma_gemm<0, 2><<<g1, 256, 0, stream>>>(hr, W1b, fb1 + i * DFF_, nullptr, ybuf,
                                              nullptr, nullptr, 2048, 512, 0);
      dim3 g2(4, R / 128);
      mfma_gemm<0, 1><<<g2, 256, 0, stream>>>(ybuf, W2b, fb2 + i * DM, nullptr, hr,
                                              nullptr, nullptr, 512, 2048, 0);
    }
    ln_inplace<<<NB * L, 256, 0, stream>>>(h, ln2g + i * DM, ln2b + i * DM);

    // ---- conv + maxpool per batch group ----
    if (i < 2) {
      int Lh = L / 2;
      for (int g = 0; g < ngroups; ++g) {
        ushort_t* hg = h + (size_t)g * segL;
        dim3 gc(4, Mg / 128);
        mfma_gemm<1, 3><<<gc, 256, 0, stream>>>(hg, Wcb, cb + i * DM, convY, nullptr,
                                                bng + i * DM, bnb + i * DM, 512, 1536, L);
        size_t tot = (size_t)CBl * Lh * 512;
        maxpool_kernel<<<(int)(tot / 256), 256, 0, stream>>>(
            convY, h + (size_t)g * CBl * Lh * 512, L);
      }
      L = Lh;
    }
  }

  final_ln_proj<<<NB * 47, 256, 0, stream>>>(h, flng, flnb, pW, pb, out, L);
}

// Round 23
// 2501.416 us; speedup vs baseline: 1.0101x; 1.0101x over previous
//
#include <hip/hip_runtime.h>
#include <cstdint>
#include <math.h>

#define NB 16
#define DM 512
#define NH 8
#define DFF_ 2048
#define SMAX 45

typedef unsigned short ushort_t;
typedef __bf16 bf16x8 __attribute__((ext_vector_type(8)));
typedef float f32x4 __attribute__((ext_vector_type(4)));

// ---------------- bf16 helpers ----------------
__device__ __forceinline__ ushort_t f2b(float f) {  // RNE f32 -> bf16 bits
  uint32_t u = __float_as_uint(f);
  uint32_t r = (u + 0x7FFFu + ((u >> 16) & 1u)) >> 16;
  return (ushort_t)r;
}
__device__ __forceinline__ float bu2f(ushort_t x) {
  return __uint_as_float((uint32_t)x << 16);
}
__device__ __forceinline__ float b2f_lo(uint32_t u) { return __uint_as_float(u << 16); }
__device__ __forceinline__ float b2f_hi(uint32_t u) { return __uint_as_float(u & 0xFFFF0000u); }
__device__ __forceinline__ uint32_t pack2(float lo, float hi) {
  return (uint32_t)f2b(lo) | ((uint32_t)f2b(hi) << 16);
}

// ---------------- threefry2x32 (JAX-compatible) ----------------
__host__ __device__ inline void tf2x32(uint32_t k0, uint32_t k1,
                                       uint32_t x0, uint32_t x1,
                                       uint32_t* o0, uint32_t* o1) {
  uint32_t ks0 = k0, ks1 = k1, ks2 = k0 ^ k1 ^ 0x1BD11BDAu;
  x0 += ks0; x1 += ks1;
#define TF_RND(r) { x0 += x1; x1 = (x1 << (r)) | (x1 >> (32 - (r))); x1 ^= x0; }
  TF_RND(13) TF_RND(15) TF_RND(26) TF_RND(6)
  x0 += ks1; x1 += ks2 + 1u;
  TF_RND(17) TF_RND(29) TF_RND(16) TF_RND(24)
  x0 += ks2; x1 += ks0 + 2u;
  TF_RND(13) TF_RND(15) TF_RND(26) TF_RND(6)
  x0 += ks0; x1 += ks1 + 3u;
  TF_RND(17) TF_RND(29) TF_RND(16) TF_RND(24)
  x0 += ks1; x1 += ks2 + 4u;
  TF_RND(13) TF_RND(15) TF_RND(26) TF_RND(6)
  x0 += ks2; x1 += ks0 + 5u;
#undef TF_RND
  *o0 = x0; *o1 = x1;
}

__global__ void gen_idx_kernel(int* __restrict__ idx, uint32_t k0, uint32_t k1,
                               int n, int mask) {
  int j = blockIdx.x * 256 + threadIdx.x;
  if (j >= n) return;
  int half = n >> 1;
  uint32_t o0, o1;
  if (j < half) {
    tf2x32(k0, k1, (uint32_t)j, (uint32_t)(j + half), &o0, &o1);
    idx[j] = (int)(o0 & (uint32_t)mask);
  } else {
    tf2x32(k0, k1, (uint32_t)(j - half), (uint32_t)j, &o0, &o1);
    idx[j] = (int)(o1 & (uint32_t)mask);
  }
}

// ---------------- block reduce helpers (256 threads, wave64) ----------------
__device__ inline float blk_reduce_sum(float v) {
  __shared__ float s[4];
  for (int o = 32; o > 0; o >>= 1) v += __shfl_down(v, o);
  int lane = threadIdx.x & 63, w = threadIdx.x >> 6;
  if (lane == 0) s[w] = v;
  __syncthreads();
  float r = s[0] + s[1] + s[2] + s[3];
  __syncthreads();
  return r;
}

// ---------------- embedding (writes bf16 h, 4 cols/thread) ----------------
__global__ void embed_kernel(const float* __restrict__ x, const float* __restrict__ W,
                             const float* __restrict__ bias, ushort_t* __restrict__ h) {
  size_t gid = (size_t)blockIdx.x * 256 + threadIdx.x;  // over NB*4096*128 quads
  int o4 = (int)(gid & 127) * 4;
  size_t bl = gid >> 7;
  const float* xr = x + bl * 7;
  float xv[7];
#pragma unroll
  for (int i = 0; i < 7; ++i) xv[i] = xr[i];
  float4 acc = *(const float4*)(bias + o4);
#pragma unroll
  for (int i = 0; i < 7; ++i) {
    float4 w4 = *(const float4*)(W + i * 512 + o4);
    acc.x += xv[i] * w4.x;
    acc.y += xv[i] * w4.y;
    acc.z += xv[i] * w4.z;
    acc.w += xv[i] * w4.w;
  }
  ushort4 o;
  o.x = f2b(acc.x); o.y = f2b(acc.y); o.z = f2b(acc.z); o.w = f2b(acc.w);
  *(ushort4*)(h + bl * 512 + o4) = o;
}

// ---------------- weight cast kernels ----------------
__global__ void cast_bf16(const float* __restrict__ src, ushort_t* __restrict__ dst,
                          size_t n) {
  size_t i = ((size_t)blockIdx.x * 256 + threadIdx.x) * 4;
  if (i >= n) return;
  float4 v = *(const float4*)(src + i);
  ushort4 o;
  o.x = f2b(v.x); o.y = f2b(v.y); o.z = f2b(v.z); o.w = f2b(v.w);
  *(ushort4*)(dst + i) = o;
}

// Bt[n*512+k] = bf16(W[k*512+n])   (512x512)
__global__ void castT512(const float* __restrict__ W, ushort_t* __restrict__ Bt) {
  int gid = blockIdx.x * 256 + threadIdx.x;
  int n = gid >> 9, k = gid & 511;
  Bt[gid] = f2b(W[(size_t)k * 512 + n]);
}

// Bt[n*1536 + dt*512 + i] = bf16(convW[n][i][dt])
__global__ void cast_convW(const float* __restrict__ W, ushort_t* __restrict__ Bt) {
  int gid = blockIdx.x * 256 + threadIdx.x;
  int n = gid / 1536, k = gid - n * 1536;
  int dt = k >> 9, ii = k & 511;
  Bt[gid] = f2b(W[((size_t)n * 512 + ii) * 3 + dt]);
}

// concat 3x512 bias -> 1536
__global__ void concat3(const float* __restrict__ a, const float* __restrict__ b,
                        const float* __restrict__ c, float* __restrict__ o) {
  int t = blockIdx.x * 256 + threadIdx.x;
  if (t >= 1536) return;
  o[t] = t < 512 ? a[t] : (t < 1024 ? b[t - 512] : c[t - 1024]);
}

// ---------------- bf16 MFMA GEMM (m97 structure + T2 XOR swizzle + T1 XCD pin) ----
__device__ __forceinline__ float gelu_exact(float c) {
  return 0.5f * c * (1.0f + erff(c * 0.70710678118654752f));
}

template <int MODE, int EPI>
__global__ __launch_bounds__(256) void mfma_gemm(
    const ushort_t* __restrict__ A, const ushort_t* __restrict__ Bt,
    const float* __restrict__ bias, float* __restrict__ Cf,
    ushort_t* __restrict__ Cb, const float* __restrict__ bng,
    const float* __restrict__ bnb, int N, int K, int L) {
  __shared__ __align__(16) ushort_t As[128 * 64];
  __shared__ __align__(16) ushort_t Bs[128 * 64];
  const int tid = threadIdx.x;
  const int lane = tid & 63;
  const int wid = tid >> 6;
  const int wr = wid >> 1, wc = wid & 1;
  // T1 XCD bm-pinning: all blocks sharing an A-row-tile (bm) land on one XCD
  int bm, bn;
  {
    int nbn = gridDim.x, nbm = gridDim.y;
    if ((nbm & 7) == 0) {
      int bid = blockIdx.y * nbn + blockIdx.x;
      int xcd = bid & 7;
      int w2 = bid >> 3;
      bm = xcd * (nbm >> 3) + w2 / nbn;
      bn = w2 % nbn;
    } else {
      bm = blockIdx.y;
      bn = blockIdx.x;
    }
  }
  const int ln = lane & 15, lh = lane >> 4;

  f32x4 acc[4][4] = {};

  for (int k0 = 0; k0 < K; k0 += 64) {
    __syncthreads();
#pragma unroll
    for (int it = 0; it < 4; ++it) {
      int c = it * 256 + tid;
      int row = c >> 3;
      int kc = (((c & 7) ^ (row & 7)) << 3);  // swizzled source chunk
      size_t ga;
      if (MODE == 1) {
        int m = bm * 128 + row;
        int b = m / L, tpos = m - b * L;
        int k = k0 + kc;
        int dt = k >> 9, ii = k & 511;
        int tr2 = tpos + dt - 1;
        if (tr2 < 0) tr2 += L;
        if (tr2 >= L) tr2 -= L;
        ga = ((size_t)(b * L + tr2)) * 512 + ii;
      } else {
        ga = (size_t)(bm * 128 + row) * K + k0 + kc;
      }
      __builtin_amdgcn_global_load_lds(
          (const __attribute__((address_space(1))) void*)(A + ga),
          (__attribute__((address_space(3))) void*)(As + c * 8), 16, 0, 0);
      size_t gb = (size_t)(bn * 128 + row) * K + k0 + kc;
      __builtin_amdgcn_global_load_lds(
          (const __attribute__((address_space(1))) void*)(Bt + gb),
          (__attribute__((address_space(3))) void*)(Bs + c * 8), 16, 0, 0);
    }
    __syncthreads();
#pragma unroll
    for (int kk = 0; kk < 2; ++kk) {
      bf16x8 af[4], bf_[4];
#pragma unroll
      for (int m = 0; m < 4; ++m) {
        int ar = wr * 64 + m * 16 + ln;
        int aoff = (kk * 32 + lh * 8) ^ ((ar & 7) << 3);
        af[m] = *(const bf16x8*)&As[ar * 64 + aoff];
      }
#pragma unroll
      for (int n = 0; n < 4; ++n) {
        int br = wc * 64 + n * 16 + ln;
        int boff = (kk * 32 + lh * 8) ^ ((br & 7) << 3);
        bf_[n] = *(const bf16x8*)&Bs[br * 64 + boff];
      }
#pragma unroll
      for (int m = 0; m < 4; ++m)
#pragma unroll
        for (int n = 0; n < 4; ++n)
          acc[m][n] =
              __builtin_amdgcn_mfma_f32_16x16x32_bf16(af[m], bf_[n], acc[m][n], 0, 0, 0);
    }
  }

  const float bnscale = 0.9999950000374996f;  // 1/sqrt(1+1e-5)
#pragma unroll
  for (int m = 0; m < 4; ++m) {
    int row = bm * 128 + wr * 64 + m * 16 + lh * 4;
#pragma unroll
    for (int n = 0; n < 4; ++n) {
      int col = bn * 128 + wc * 64 + n * 16 + ln;
      float bsv = bias[col];
#pragma unroll
      for (int r = 0; r < 4; ++r) {
        float cval = acc[m][n][r] + bsv;
        if (MODE == 2) {
          ushort_t* dst = Cb + (size_t)(bn >> 2) * (size_t)L;  // L = CBseg
          dst[(size_t)(row + r) * 512 + (col & 511)] = f2b(cval);
        } else {
          size_t oi = (size_t)(row + r) * N + col;
          if (EPI == 0) {
            Cb[oi] = f2b(cval);
          } else if (EPI == 1) {
            Cb[oi] = f2b(cval + bu2f(Cb[oi]));
          } else if (EPI == 2) {
            Cb[oi] = f2b(gelu_exact(cval));
          } else {
            float c2 = cval * bnscale * bng[col] + bnb[col];
            Cf[oi] = c2 > 0.0f ? c2 : expm1f(c2);
          }
        }
      }
    }
  }
}

// ---------------- LN (in-place on bf16 h, packed uint per thread) ----------------
__global__ __launch_bounds__(256) void ln_inplace(ushort_t* __restrict__ h,
                                                  const float* __restrict__ g,
                                                  const float* __restrict__ b) {
  size_t row = blockIdx.x;
  uint32_t* hr = (uint32_t*)(h + row * 512);
  int t = threadIdx.x;
  uint32_t u = hr[t];
  float x0 = b2f_lo(u), x1 = b2f_hi(u);
  float mean = blk_reduce_sum(x0 + x1) * (1.0f / 512.0f);
  float d0 = x0 - mean, d1 = x1 - mean;
  float var = blk_reduce_sum(d0 * d0 + d1 * d1) * (1.0f / 512.0f);
  float rstd = rsqrtf(var + 1e-5f);
  float y0 = d0 * rstd * g[2 * t] + b[2 * t];
  float y1 = d1 * rstd * g[2 * t + 1] + b[2 * t + 1];
  hr[t] = pack2(y0, y1);
}

// ---------------- prob-sparse M scores: one wave per (b,l), 5-way unrolled -------
__device__ __forceinline__ float dot8q(const float* __restrict__ qf, uint4 ku) {
  return qf[0] * b2f_lo(ku.x) + qf[1] * b2f_hi(ku.x) +
         qf[2] * b2f_lo(ku.y) + qf[3] * b2f_hi(ku.y) +
         qf[4] * b2f_lo(ku.z) + qf[5] * b2f_hi(ku.z) +
         qf[6] * b2f_lo(ku.w) + qf[7] * b2f_hi(ku.w);
}

__global__ __launch_bounds__(256) void prob_scores_wave(const ushort_t* __restrict__ q,
                                                        const ushort_t* __restrict__ k,
                                                        const int* __restrict__ idx,
                                                        float* __restrict__ Mout,
                                                        int L, int S, int CBl) {
  int bid = blockIdx.x;
  int w = threadIdx.x >> 6;
  int lane = threadIdx.x & 63;
  int nxb = CBl < 8 ? CBl : 8;
  int gpb = 8 / nxb;
  int bmul = CBl / nxb;
  int xcd = bid & 7;
  int rest = bid >> 3;
  int b = (xcd / gpb) * bmul + (rest % bmul);
  int li = (rest / bmul) * gpb + (xcd % gpb);
  int l = li * 4 + w;

  const ushort_t* qr = q + ((size_t)(b * L + l)) * 512 + lane * 8;
  uint4 qu = *(const uint4*)qr;
  float qf[8];
  qf[0] = b2f_lo(qu.x); qf[1] = b2f_hi(qu.x);
  qf[2] = b2f_lo(qu.y); qf[3] = b2f_hi(qu.y);
  qf[4] = b2f_lo(qu.z); qf[5] = b2f_hi(qu.z);
  qf[6] = b2f_lo(qu.w); qf[7] = b2f_hi(qu.w);
  const int* il = idx + l * S;
  const ushort_t* kb = k + (size_t)b * L * 512 + lane * 8;
  float m = -INFINITY, ssum = 0.0f;
  for (int s = 0; s < S; s += 5) {
    uint4 k0v = *(const uint4*)(kb + (size_t)il[s + 0] * 512);
    uint4 k1v = *(const uint4*)(kb + (size_t)il[s + 1] * 512);
    uint4 k2v = *(const uint4*)(kb + (size_t)il[s + 2] * 512);
    uint4 k3v = *(const uint4*)(kb + (size_t)il[s + 3] * 512);
    uint4 k4v = *(const uint4*)(kb + (size_t)il[s + 4] * 512);
    float d0 = dot8q(qf, k0v);
    float d1 = dot8q(qf, k1v);
    float d2 = dot8q(qf, k2v);
    float d3 = dot8q(qf, k3v);
    float d4 = dot8q(qf, k4v);
    d0 += __shfl_xor(d0, 1); d1 += __shfl_xor(d1, 1); d2 += __shfl_xor(d2, 1);
    d3 += __shfl_xor(d3, 1); d4 += __shfl_xor(d4, 1);
    d0 += __shfl_xor(d0, 2); d1 += __shfl_xor(d1, 2); d2 += __shfl_xor(d2, 2);
    d3 += __shfl_xor(d3, 2); d4 += __shfl_xor(d4, 2);
    d0 += __shfl_xor(d0, 4); d1 += __shfl_xor(d1, 4); d2 += __shfl_xor(d2, 4);
    d3 += __shfl_xor(d3, 4); d4 += __shfl_xor(d4, 4);
    m = fmaxf(m, fmaxf(fmaxf(d0, d1), fmaxf(d2, fmaxf(d3, d4))));
    ssum += (d0 + d1) + (d2 + (d3 + d4));
  }
  if ((lane & 7) == 0) {
    int hh = lane >> 3;
    Mout[((size_t)(b * 8 + hh)) * L + l] = m - ssum / (float)L;
  }
}

// ---------------- top-k via 4-pass radix select ----------------
__global__ __launch_bounds__(256) void topk_kernel(const float* __restrict__ Mbuf,
                                                   int* __restrict__ top_idx,
                                                   int L, int S) {
  int bh = blockIdx.x;
  __shared__ uint32_t keys[4096];
  __shared__ int hist[256];
  __shared__ int sh_bin, sh_found, sh_cnt;
  const float* Mr = Mbuf + (size_t)bh * L;
  int t = threadIdx.x;

  for (int j = t; j < L; j += 256) {
    uint32_t u = __float_as_uint(Mr[j]);
    keys[j] = (u & 0x80000000u) ? ~u : (u | 0x80000000u);
  }
  if (t == 0) sh_cnt = 0;
  __syncthreads();

  uint32_t prefix = 0;
  int found = 0;
  for (int p = 24; p >= 0; p -= 8) {
    hist[t] = 0;
    __syncthreads();
    for (int j = t; j < L; j += 256) {
      uint32_t key = keys[j];
      bool match = (p == 24) || ((key >> (p + 8)) == (prefix >> (p + 8)));
      if (match) atomicAdd(&hist[(key >> p) & 255], 1);
    }
    __syncthreads();
    for (int o = 1; o < 256; o <<= 1) {
      int add = (t + o < 256) ? hist[t + o] : 0;
      __syncthreads();
      hist[t] += add;
      __syncthreads();
    }
    int sufIncl = hist[t];
    int sufExcl = (t < 255) ? hist[t + 1] : 0;
    int needv = S - found;
    if (sufExcl < needv && needv <= sufIncl) { sh_bin = t; sh_found = found + sufExcl; }
    __syncthreads();
    prefix |= (uint32_t)sh_bin << p;
    found = sh_found;
    __syncthreads();
  }

  uint32_t tau = prefix;
  int r = S - found;
  int chunk = L >> 8;
  int base = t * chunk;
  int localEq = 0;
  for (int i = 0; i < chunk; ++i) localEq += (keys[base + i] == tau) ? 1 : 0;
  hist[t] = localEq;
  __syncthreads();
  for (int o = 1; o < 256; o <<= 1) {
    int add = (t >= o) ? hist[t - o] : 0;
    __syncthreads();
    hist[t] += add;
    __syncthreads();
  }
  int myRank = hist[t] - localEq;
  for (int i = 0; i < chunk; ++i) {
    uint32_t key = keys[base + i];
    bool isEq = (key == tau);
    bool sel = (key > tau) || (isEq && myRank < r);
    if (isEq) myRank++;
    if (sel) {
      int slot = atomicAdd(&sh_cnt, 1);
      top_idx[bh * S + slot] = base + i;
    }
  }
}

// ---------------- mean of V: stage 1 (coalesced column partial sums) ----------------
__global__ __launch_bounds__(256) void mean_v_partial(const ushort_t* __restrict__ v,
                                                      float* __restrict__ part, int L) {
  int b = blockIdx.x;
  int chunk = blockIdx.y;
  int t = threadIdx.x;
  int c = t * 2;
  const ushort_t* base = v + ((size_t)b * L + (size_t)chunk * 256) * 512 + c;
  float a0 = 0.0f, a1 = 0.0f;
#pragma unroll 8
  for (int r = 0; r < 256; ++r) {
    uint32_t u = *(const uint32_t*)(base + (size_t)r * 512);
    a0 += b2f_lo(u);
    a1 += b2f_hi(u);
  }
  float* p = part + ((size_t)b * 16 + chunk) * 512 + c;
  p[0] = a0;
  p[1] = a1;
}

// ---------------- mean of V: stage 2 ----------------
__global__ void mean_v_finish(const float* __restrict__ part, float* __restrict__ mv,
                              int L, int nchunks) {
  int b = blockIdx.x;
  int c = threadIdx.x;  // 512 threads
  float s = 0.0f;
  for (int k = 0; k < nchunks; ++k) s += part[((size_t)b * 16 + k) * 512 + c];
  mv[b * 512 + c] = s / (float)L;
}

// ---------------- fill ctx (bf16) with broadcast mean ----------------
__global__ void fill_ctx(ushort_t* __restrict__ ctx, const float* __restrict__ mv,
                         int L) {
  size_t gid = (size_t)blockIdx.x * 256 + threadIdx.x;  // CB*L*512
  int c = (int)(gid & 511);
  size_t bl = gid >> 9;
  int b = (int)(bl / (size_t)L);
  ctx[gid] = f2b(mv[b * 512 + c]);
}

// ---------------- fused flash attention (MFMA QK^T + PV; no-max softmax) ----------
__global__ __launch_bounds__(256) void flash_attn(const ushort_t* __restrict__ q,
                                                  const ushort_t* __restrict__ k,
                                                  const ushort_t* __restrict__ v,
                                                  const int* __restrict__ top_idx,
                                                  float* __restrict__ pz,
                                                  float* __restrict__ po,
                                                  int L, int S, int CBNH) {
  __shared__ __align__(16) ushort_t qs[48 * 64];   // [query][d]
  __shared__ __align__(16) ushort_t Kt[64 * 64];   // [key][d]
  __shared__ __align__(16) ushort_t Vt[64 * 64];   // [d][key] (transposed)
  __shared__ __align__(16) ushort_t Ps[48 * 64];   // [query][key] bf16
  __shared__ float zpart[4][48];
  int bh = blockIdx.y, js = blockIdx.x;
  int hh = bh & 7, b = bh >> 3;
  int t = threadIdx.x;
  int lane = t & 63, w = t >> 6;
  int ln = lane & 15, lh = lane >> 4;
  int j0 = js * 64;

  // stage qs: 48 rows x 8 chunks, zero-pad rows >= S
  for (int e = t; e < 48 * 8; e += 256) {
    int u = e >> 3, c = e & 7;
    uint4 val = make_uint4(0u, 0u, 0u, 0u);
    if (u < S) {
      int l = top_idx[bh * S + u];
      val = *(const uint4*)(q + ((size_t)(b * L + l)) * 512 + hh * 64 + c * 8);
    }
    *(uint4*)(qs + u * 64 + ((c ^ (u & 7)) << 3)) = val;
  }
  // stage Kt [key][d] and Vt [d][key]
  for (int e = t; e < 64 * 8; e += 256) {
    int j = e >> 3, c = e & 7;
    uint4 kv = *(const uint4*)(k + ((size_t)(b * L + j0 + j)) * 512 + hh * 64 + c * 8);
    *(uint4*)(Kt + j * 64 + ((c ^ (j & 7)) << 3)) = kv;
    uint4 vv = *(const uint4*)(v + ((size_t)(b * L + j0 + j)) * 512 + hh * 64 + c * 8);
    const ushort_t* pv8 = (const ushort_t*)&vv;
#pragma unroll
    for (int ee = 0; ee < 8; ++ee) {
      int d = c * 8 + ee;
      Vt[d * 64 + (((j >> 3) ^ (d & 7)) << 3) + (j & 7)] = pv8[ee];
    }
  }
  __syncthreads();

  // ---- QK^T: wave w owns key tile [w*16, w*16+16) ----
  f32x4 sacc[3] = {};
#pragma unroll
  for (int kk = 0; kk < 2; ++kk) {
    int j = w * 16 + ln;
    bf16x8 bfr = *(const bf16x8*)&Kt[j * 64 + (((kk * 4 + lh) ^ (j & 7)) << 3)];
#pragma unroll
    for (int qm = 0; qm < 3; ++qm) {
      int u = qm * 16 + ln;
      bf16x8 af = *(const bf16x8*)&qs[u * 64 + (((kk * 4 + lh) ^ (u & 7)) << 3)];
      sacc[qm] = __builtin_amdgcn_mfma_f32_16x16x32_bf16(af, bfr, sacc[qm], 0, 0, 0);
    }
  }
  // P = exp(S/8) -> bf16 Ps; z partials per 16-lane group
#pragma unroll
  for (int qm = 0; qm < 3; ++qm) {
#pragma unroll
    for (int r = 0; r < 4; ++r) {
      int u = qm * 16 + lh * 4 + r;
      float P = __expf(sacc[qm][r] * 0.125f);
      ushort_t Pb = f2b(P);
      int key = w * 16 + ln;
      Ps[u * 64 + (((key >> 3) ^ (u & 7)) << 3) + (key & 7)] = Pb;
      float ps = bu2f(Pb);
      ps += __shfl_xor(ps, 1);
      ps += __shfl_xor(ps, 2);
      ps += __shfl_xor(ps, 4);
      ps += __shfl_xor(ps, 8);
      if (ln == 0) zpart[w][u] = ps;
    }
  }
  __syncthreads();

  // ---- PV: wave w owns d tile [w*16, w*16+16) ----
  f32x4 oacc[3] = {};
#pragma unroll
  for (int kk = 0; kk < 2; ++kk) {
    int d = w * 16 + ln;
    bf16x8 bfr = *(const bf16x8*)&Vt[d * 64 + (((kk * 4 + lh) ^ (d & 7)) << 3)];
#pragma unroll
    for (int qm = 0; qm < 3; ++qm) {
      int u = qm * 16 + ln;
      bf16x8 af = *(const bf16x8*)&Ps[u * 64 + (((kk * 4 + lh) ^ (u & 7)) << 3)];
      oacc[qm] = __builtin_amdgcn_mfma_f32_16x16x32_bf16(af, bfr, oacc[qm], 0, 0, 0);
    }
  }
  size_t base = (size_t)js * CBNH + bh;
#pragma unroll
  for (int qm = 0; qm < 3; ++qm) {
#pragma unroll
    for (int r = 0; r < 4; ++r) {
      int u = qm * 16 + lh * 4 + r;
      if (u < S) po[(base * SMAX + u) * 64 + w * 16 + ln] = oacc[qm][r];
    }
  }
  if (t < S) pz[base * SMAX + t] =
      zpart[0][t] + zpart[1][t] + zpart[2][t] + zpart[3][t];
}

// ---------------- combine flash partials, /Z, scatter into ctx ----------------
__global__ void flash_finish(const float* __restrict__ pz, const float* __restrict__ po,
                             const int* __restrict__ top_idx, ushort_t* __restrict__ ctx,
                             int L, int S, int CBNH, int fj) {
  int gid = blockIdx.x * 256 + threadIdx.x;  // over CBNH*S*64
  if (gid >= CBNH * S * 64) return;
  int d = gid & 63;
  int r = gid >> 6;  // bh*S + u
  int u = r % S, bh = r / S;
  int hh = bh & 7, b = bh >> 3;
  float Z = 0.0f, O = 0.0f;
  for (int js = 0; js < fj; ++js) {
    size_t pi = ((size_t)js * CBNH + bh) * SMAX + u;
    Z += pz[pi];
    O += po[pi * 64 + d];
  }
  int l = top_idx[bh * S + u];
  ctx[((size_t)(b * L + l)) * 512 + hh * 64 + d] = f2b(O / Z);
}

// ---------------- maxpool window 3 stride 2 (f32 in, bf16 out) ----------------
__global__ void maxpool_kernel(const float* __restrict__ y, ushort_t* __restrict__ hout,
                               int L) {
  size_t gid = (size_t)blockIdx.x * 256 + threadIdx.x;  // CB*(L/2)*512
  int Lh = L >> 1;
  int o = (int)(gid & 511);
  size_t bj = gid >> 9;
  int j = (int)(bj % (size_t)Lh);
  int b = (int)(bj / (size_t)Lh);
  const float* base = y + ((size_t)(b * L + 2 * j)) * 512 + o;
  float mx = base[0];
  if (j > 0) mx = fmaxf(mx, base[-512]);
  mx = fmaxf(mx, base[512]);
  hout[gid] = f2b(mx);
}

// ---------------- final LN + projection (bf16 h) ----------------
__global__ __launch_bounds__(256) void final_ln_proj(const ushort_t* __restrict__ h,
                                                     const float* __restrict__ g,
                                                     const float* __restrict__ bb,
                                                     const float* __restrict__ pw,
                                                     const float* __restrict__ pb,
                                                     float* __restrict__ out, int L) {
  int b = blockIdx.x / 47, l = blockIdx.x % 47;
  const uint32_t* hr = (const uint32_t*)(h + ((size_t)(b * L + l)) * 512);
  int t = threadIdx.x;
  uint32_t u = hr[t];
  float x0 = b2f_lo(u), x1 = b2f_hi(u);
  float mean = blk_reduce_sum(x0 + x1) * (1.0f / 512.0f);
  float d0 = x0 - mean, d1 = x1 - mean;
  float var = blk_reduce_sum(d0 * d0 + d1 * d1) * (1.0f / 512.0f);
  float rstd = rsqrtf(var + 1e-5f);
  float y0 = d0 * rstd * g[2 * t] + bb[2 * t];
  float y1 = d1 * rstd * g[2 * t + 1] + bb[2 * t + 1];
  float dot = blk_reduce_sum(y0 * pw[2 * t] + y1 * pw[2 * t + 1]);
  if (t == 0) out[b * 47 + l] = dot + pb[0];
}

// ---------------- launcher ----------------
extern "C" void kernel_launch(void* const* d_in, const int* in_sizes, int n_in,
                              void* d_out, int out_size, void* d_ws, size_t ws_size,
                              hipStream_t stream) {
  const float* x = (const float*)d_in[0];
  const float* emb_W = (const float*)d_in[1];
  const float* emb_b = (const float*)d_in[2];
  const float* Wq = (const float*)d_in[3];
  const float* bq = (const float*)d_in[4];
  const float* Wk = (const float*)d_in[5];
  const float* bk = (const float*)d_in[6];
  const float* Wv = (const float*)d_in[7];
  const float* bv = (const float*)d_in[8];
  const float* Wo = (const float*)d_in[9];
  const float* bo = (const float*)d_in[10];
  const float* fW1 = (const float*)d_in[11];
  const float* fb1 = (const float*)d_in[12];
  const float* fW2 = (const float*)d_in[13];
  const float* fb2 = (const float*)d_in[14];
  const float* ln1g = (const float*)d_in[15];
  const float* ln1b = (const float*)d_in[16];
  const float* ln2g = (const float*)d_in[17];
  const float* ln2b = (const float*)d_in[18];
  const float* cW = (const float*)d_in[19];
  const float* cb = (const float*)d_in[20];
  const float* bng = (const float*)d_in[21];
  const float* bnb = (const float*)d_in[22];
  const float* flng = (const float*)d_in[23];
  const float* flnb = (const float*)d_in[24];
  const float* pW = (const float*)d_in[25];
  const float* pb = (const float*)d_in[26];
  float* out = (float*)d_out;

  // base batch-group size from ws_size (try 16, 8, 4, 2, 1)
  // need(CB0) = 19,086,848 + CB0 * 5,724,672 floats
  int CB0 = 16;
  while (CB0 > 1) {
    size_t need = 19086848ull + (size_t)CB0 * 5724672ull;
    if (need * 4 <= ws_size) break;
    CB0 >>= 1;
  }
  const size_t CBseg = (size_t)CB0 * 2097152ull;  // CB0*4096*512 (bf16 elems)

  float* ws = (float*)d_ws;
  size_t off = 0;
  ushort_t* h = (ushort_t*)ws;             off += 16777216ull;  // NB*4096*512 bf16
  ushort_t* wbase = (ushort_t*)(ws + off); off += 1966080ull;
  ushort_t* WqkvT = wbase;                 // 1536 x 512 (q rows, k rows, v rows)
  ushort_t* WoT = wbase + 786432;
  ushort_t* W1b = wbase + 1048576;
  ushort_t* W2b = wbase + 2097152;
  ushort_t* Wcb = wbase + 3145728;
  float* bqkv = ws + off;                  off += 1536ull;
  ushort_t* gArea = (ushort_t*)(ws + off); off += 2ull * CBseg;  // 4 segs bf16
  ushort_t* qb = gArea;
  ushort_t* kbuf = gArea + CBseg;
  ushort_t* vb = gArea + 2 * CBseg;
  ushort_t* ctxb = gArea + 3 * CBseg;
  ushort_t* ybuf = gArea;        // spans all 4 segs during FF (R x 2048 bf16)
  float* convY = (float*)gArea;  // spans first 2 segs during conv (CBseg f32)
  float* Mbuf = ws + off;                  off += (size_t)CB0 * 32768;
  float* mv = ws + off;                    off += 8192ull;
  int* topidx = (int*)(ws + off);          off += 6144ull;
  int* idxbuf = (int*)(ws + off);          off += 196608ull;
  float* pzb = ws + off;                   off += (size_t)CB0 * 23040;
  float* pob = ws + off;                   off += (size_t)CB0 * 1474560;
  float* mvpart = ws + off;                off += 131072ull;

  // embedding (bf16 h)
  {
    size_t total = (size_t)NB * 4096 * 128;
    embed_kernel<<<(int)(total / 256), 256, 0, stream>>>(x, emb_W, emb_b, h);
  }

  int L = 4096;
  for (int i = 0; i < 3; ++i) {
    int S = (i == 0) ? 45 : (i == 1) ? 40 : 35;
    int CBl = CB0 * (4096 / L);
    if (CBl > NB) CBl = NB;
    int ngroups = NB / CBl;
    int CBNHl = CBl * NH;
    int Mg = CBl * L;
    size_t segL = (size_t)Mg * 512;
    int fj = L / 64;

    // per-layer weight casts
    castT512<<<1024, 256, 0, stream>>>(Wq + (size_t)i * 262144, WqkvT);
    castT512<<<1024, 256, 0, stream>>>(Wk + (size_t)i * 262144, WqkvT + 262144);
    castT512<<<1024, 256, 0, stream>>>(Wv + (size_t)i * 262144, WqkvT + 524288);
    castT512<<<1024, 256, 0, stream>>>(Wo + (size_t)i * 262144, WoT);
    cast_bf16<<<1024, 256, 0, stream>>>(fW1 + (size_t)i * 1048576, W1b, 1048576);
    cast_bf16<<<1024, 256, 0, stream>>>(fW2 + (size_t)i * 1048576, W2b, 1048576);
    if (i < 2) cast_convW<<<3072, 256, 0, stream>>>(cW + (size_t)i * 786432, Wcb);
    concat3<<<6, 256, 0, stream>>>(bq + i * DM, bk + i * DM, bv + i * DM, bqkv);

    // JAX randint key
    uint32_t fa, fbk;
    tf2x32(0u, 42u, 0u, (uint32_t)i, &fa, &fbk);
    uint32_t a0, b0, a1, b1;
    tf2x32(fa, fbk, 0u, 2u, &a0, &b0);
    tf2x32(fa, fbk, 1u, 3u, &a1, &b1);
    int n = L * S;
    gen_idx_kernel<<<(n + 255) / 256, 256, 0, stream>>>(idxbuf, b0, b1, n, L - 1);

    // ---- attention per batch group ----
    for (int g = 0; g < ngroups; ++g) {
      ushort_t* hg = h + (size_t)g * segL;
      dim3 gqkv(12, Mg / 128);
      mfma_gemm<2, 0><<<gqkv, 256, 0, stream>>>(hg, WqkvT, bqkv, nullptr, qb,
                                                nullptr, nullptr, 1536, 512,
                                                (int)CBseg);

      prob_scores_wave<<<(CBl * L) / 4, 256, 0, stream>>>(qb, kbuf, idxbuf, Mbuf,
                                                          L, S, CBl);
      topk_kernel<<<CBNHl, 256, 0, stream>>>(Mbuf, topidx, L, S);

      mean_v_partial<<<dim3(CBl, L / 256), 256, 0, stream>>>(vb, mvpart, L);
      mean_v_finish<<<CBl, 512, 0, stream>>>(mvpart, mv, L, L / 256);
      fill_ctx<<<(int)(segL / 256), 256, 0, stream>>>(ctxb, mv, L);
      flash_attn<<<dim3(fj, CBNHl), 256, 0, stream>>>(qb, kbuf, vb, topidx,
                                                      pzb, pob, L, S, CBNHl);
      flash_finish<<<(CBNHl * S * 64 + 255) / 256, 256, 0, stream>>>(
          pzb, pob, topidx, ctxb, L, S, CBNHl, fj);

      dim3 gq(4, Mg / 128);
      mfma_gemm<0, 1><<<gq, 256, 0, stream>>>(ctxb, WoT, bo + i * DM, nullptr, hg,
                                              nullptr, nullptr, 512, 512, 0);
    }
    ln_inplace<<<NB * L, 256, 0, stream>>>(h, ln1g + i * DM, ln1b + i * DM);

    // ---- FF row-chunked ----
    int rows = NB * L;
    int R = CB0 * 4096;
    if (R > rows) R = rows;
    for (int r0 = 0; r0 < rows; r0 += R) {
      ushort_t* hr = h + (size_t)r0 * 512;
      dim3 g1(16, R / 128);
      mfma_gemm<0, 2><<<g1, 256, 0, stream>>>(hr, W1b, fb1 + i * DFF_, nullptr, ybuf,
                                              nullptr, nullptr, 2048, 512, 0);
      dim3 g2(4, R / 128);
      mfma_gemm<0, 1><<<g2, 256, 0, stream>>>(ybuf, W2b, fb2 + i * DM, nullptr, hr,
                                              nullptr, nullptr, 512, 2048, 0);
    }
    ln_inplace<<<NB * L, 256, 0, stream>>>(h, ln2g + i * DM, ln2b + i * DM);

    // ---- conv + maxpool per batch group ----
    if (i < 2) {
      int Lh = L / 2;
      for (int g = 0; g < ngroups; ++g) {
        ushort_t* hg = h + (size_t)g * segL;
        dim3 gc(4, Mg / 128);
        mfma_gemm<1, 3><<<gc, 256, 0, stream>>>(hg, Wcb, cb + i * DM, convY, nullptr,
                                                bng + i * DM, bnb + i * DM, 512, 1536, L);
        size_t tot = (size_t)CBl * Lh * 512;
        maxpool_kernel<<<(int)(tot / 256), 256, 0, stream>>>(
            convY, h + (size_t)g * CBl * Lh * 512, L);
      }
      L = Lh;
    }
  }

  final_ln_proj<<<NB * 47, 256, 0, stream>>>(h, flng, flnb, pW, pb, out, L);
}